// Round 1
// baseline (101.494 us; speedup 1.0000x reference)
//
#include <hip/hip_runtime.h>
#include <hip/hip_bf16.h>

#define M_DIM 4096
#define N_DIM 8192
#define D_DIM 256
#define BM 128
#define BN 128
#define TILE_BYTES (BM * D_DIM * 2) /* 65536 B: one tile, row-major, 512 B rows */

typedef __attribute__((ext_vector_type(8))) short short8; // 8 bf16 = 4 VGPR
typedef __attribute__((ext_vector_type(4))) float f32x4;  // MFMA C/D frag

__device__ inline unsigned short f2bf(float f) {
    __hip_bfloat16 h = __float2bfloat16(f);
    return *reinterpret_cast<unsigned short*>(&h);
}

// ---------------------------------------------------------------------------
// prep: fp32 -> bf16 rows for X and X_train, per-row sum-of-squares, zero out.
// One wave per row (64 lanes x float4 = 256 elems).
// ---------------------------------------------------------------------------
__global__ __launch_bounds__(256) void prep_kernel(
    const float* __restrict__ X, const float* __restrict__ T,
    unsigned short* __restrict__ Xb, unsigned short* __restrict__ Tb,
    float* __restrict__ sq1, float* __restrict__ sq2,
    float* __restrict__ out)
{
    const int gid = blockIdx.x * 256 + threadIdx.x;
    if (gid < M_DIM) out[gid] = 0.0f;            // zero the output accumulator

    const int row  = blockIdx.x * 4 + (threadIdx.x >> 6);
    const int lane = threadIdx.x & 63;
    const float* src; unsigned short* dst; float* sqp; int r;
    if (row < M_DIM) { src = X; dst = Xb; sqp = sq1; r = row; }
    else             { src = T; dst = Tb; sqp = sq2; r = row - M_DIM; }

    const float4* s4 = reinterpret_cast<const float4*>(src + (size_t)r * D_DIM);
    float4 v = s4[lane];
    float ss = v.x * v.x + v.y * v.y + v.z * v.z + v.w * v.w;

    ushort4 b4;
    b4.x = f2bf(v.x); b4.y = f2bf(v.y); b4.z = f2bf(v.z); b4.w = f2bf(v.w);
    reinterpret_cast<ushort4*>(dst + (size_t)r * D_DIM)[lane] = b4;

    #pragma unroll
    for (int o = 1; o < 64; o <<= 1) ss += __shfl_xor(ss, o);
    if (lane == 0) sqp[r] = ss;
}

// ---------------------------------------------------------------------------
// Fused RBF GEMM: S = Xb @ Tb^T (bf16 MFMA, fp32 acc), epilogue
// pred[i] += sum_j exp(-(sq1[i]+sq2[j]-2S)/2) * alpha[j]  via shuffle-reduce
// + atomicAdd. Full K=256 resident in LDS (no K loop over tiles).
// LDS layout: row-major [128][512B] with XOR swizzle byte^=((row&7)<<4)
// (linear global_load_lds dest + inverse-swizzled global source, G21).
// ---------------------------------------------------------------------------
__global__ __launch_bounds__(256) void gemm_kernel(
    const unsigned short* __restrict__ Xb, const unsigned short* __restrict__ Tb,
    const float* __restrict__ sq1, const float* __restrict__ sq2,
    const float* __restrict__ alpha, float* __restrict__ out)
{
    __shared__ __align__(16) char smem[2 * TILE_BYTES]; // 128 KiB
    char* As = smem;
    char* Bs = smem + TILE_BYTES;

    const int bm   = blockIdx.x & 31;   // M/BM = 32 (fastest: share B tile in L2)
    const int bn   = blockIdx.x >> 5;   // N/BN = 64
    const int tid  = threadIdx.x;
    const int wid  = tid >> 6;          // wave 0..3
    const int lane = tid & 63;

    // Tiles are 128 consecutive full rows -> contiguous 64 KiB in global.
    const char* gA = (const char*)(Xb + (size_t)bm * BM * D_DIM);
    const char* gB = (const char*)(Tb + (size_t)bn * BN * D_DIM);

    // Stage both tiles: 64 chunks of 1 KiB each per tile, 16 chunks/wave.
    // LDS dest linear (wave base + lane*16); source pre-inverse-swizzled.
    #pragma unroll
    for (int c = 0; c < 16; ++c) {
        const int ob = (wid * 16 + c) * 1024;             // wave-uniform
        const int o  = ob + lane * 16;                    // per-lane tile offset
        const int so = o ^ (((o >> 9) & 7) << 4);         // involution swizzle
        __builtin_amdgcn_global_load_lds(
            (const __attribute__((address_space(1))) void*)(gA + so),
            (__attribute__((address_space(3))) void*)(As + ob), 16, 0, 0);
        __builtin_amdgcn_global_load_lds(
            (const __attribute__((address_space(1))) void*)(gB + so),
            (__attribute__((address_space(3))) void*)(Bs + ob), 16, 0, 0);
    }
    __syncthreads(); // drains vmcnt before ds_read

    const int wr  = wid >> 1, wc = wid & 1;  // 2x2 waves, 64x64 out each
    const int l15 = lane & 15;
    const int lg  = lane >> 4;
    const int xm  = (lane & 7) << 4;         // swizzle mask (row&7 == lane&7)
    const int klo = lg << 4;                 // k-group byte offset

    f32x4 acc[4][4];
    #pragma unroll
    for (int m = 0; m < 4; ++m)
        #pragma unroll
        for (int n = 0; n < 4; ++n) acc[m][n] = (f32x4)0.0f;

    int abase[4], bbase[4];
    #pragma unroll
    for (int m = 0; m < 4; ++m) abase[m] = (wr * 64 + m * 16 + l15) * 512;
    #pragma unroll
    for (int n = 0; n < 4; ++n) bbase[n] = (wc * 64 + n * 16 + l15) * 512;

    #pragma unroll
    for (int kk = 0; kk < 8; ++kk) {
        const int kb = (kk * 64 + klo) ^ xm; // swizzled k-byte (shared a/b)
        short8 af[4], bf[4];
        #pragma unroll
        for (int m = 0; m < 4; ++m) af[m] = *(const short8*)(As + abase[m] + kb);
        #pragma unroll
        for (int n = 0; n < 4; ++n) bf[n] = *(const short8*)(Bs + bbase[n] + kb);
        #pragma unroll
        for (int m = 0; m < 4; ++m)
            #pragma unroll
            for (int n = 0; n < 4; ++n)
                acc[m][n] = __builtin_amdgcn_mfma_f32_16x16x32_bf16(
                    af[m], bf[n], acc[m][n], 0, 0, 0);
    }

    // Epilogue: C/D layout col=lane&15, row=(lane>>4)*4+reg (m89-verified).
    const int brow = bm * BM, bcol = bn * BN;
    float sq2c[4], alf[4];
    #pragma unroll
    for (int n = 0; n < 4; ++n) {
        const int gj = bcol + wc * 64 + n * 16 + l15;
        sq2c[n] = sq2[gj];
        alf[n]  = alpha[gj];
    }
    #pragma unroll
    for (int m = 0; m < 4; ++m) {
        #pragma unroll
        for (int r = 0; r < 4; ++r) {
            const int gi = brow + wr * 64 + m * 16 + lg * 4 + r;
            const float s1 = sq1[gi];
            float p = 0.0f;
            #pragma unroll
            for (int n = 0; n < 4; ++n) {
                const float d = s1 + sq2c[n] - 2.0f * acc[m][n][r];
                p += __expf(-0.5f * d) * alf[n];
            }
            // reduce over the 16 lanes holding this row's 64 columns
            p += __shfl_xor(p, 1);
            p += __shfl_xor(p, 2);
            p += __shfl_xor(p, 4);
            p += __shfl_xor(p, 8);
            if (l15 == 0) atomicAdd(&out[gi], p);
        }
    }
}

extern "C" void kernel_launch(void* const* d_in, const int* in_sizes, int n_in,
                              void* d_out, int out_size, void* d_ws, size_t ws_size,
                              hipStream_t stream)
{
    const float* X  = (const float*)d_in[0];
    const float* T  = (const float*)d_in[1];
    const float* al = (const float*)d_in[2];
    float* out = (float*)d_out;

    char* ws = (char*)d_ws;
    unsigned short* Xb = (unsigned short*)ws;                              // 2 MiB
    unsigned short* Tb = (unsigned short*)(ws + (size_t)M_DIM * D_DIM * 2); // 4 MiB
    float* sq1 = (float*)(ws + (size_t)(M_DIM + N_DIM) * D_DIM * 2);       // 16 KiB
    float* sq2 = sq1 + M_DIM;                                              // 32 KiB

    prep_kernel<<<(M_DIM + N_DIM) / 4, 256, 0, stream>>>(X, T, Xb, Tb, sq1, sq2, out);
    gemm_kernel<<<(M_DIM / BM) * (N_DIM / BN), 256, 0, stream>>>(Xb, Tb, sq1, sq2, al, out);
}

// Round 2
// 56.496 us; speedup vs baseline: 1.7965x; 1.7965x over previous
//
#include <hip/hip_runtime.h>
#include <hip/hip_bf16.h>

#define M_DIM 4096
#define N_DIM 8192
#define D_DIM 256
#define BM 128
#define BN 128
#define BK 64                       /* K-step: 4 steps over D=256 */
#define STEP_BYTES (BM * BK * 2)    /* 16 KiB per tile per step, 128 B rows */

typedef __attribute__((ext_vector_type(8))) short short8; // 8 bf16 = 4 VGPR
typedef __attribute__((ext_vector_type(4))) float f32x4;  // MFMA C/D frag

__device__ inline unsigned short f2bf(float f) {
    __hip_bfloat16 h = __float2bfloat16(f);
    return *reinterpret_cast<unsigned short*>(&h);
}

// ---------------------------------------------------------------------------
// prep: fp32 -> bf16 rows for X and X_train, per-row sum-of-squares, zero out.
// One wave per row (64 lanes x float4 = 256 elems).
// ---------------------------------------------------------------------------
__global__ __launch_bounds__(256) void prep_kernel(
    const float* __restrict__ X, const float* __restrict__ T,
    unsigned short* __restrict__ Xb, unsigned short* __restrict__ Tb,
    float* __restrict__ sq1, float* __restrict__ sq2,
    float* __restrict__ out)
{
    const int gid = blockIdx.x * 256 + threadIdx.x;
    if (gid < M_DIM) out[gid] = 0.0f;            // zero the output accumulator

    const int row  = blockIdx.x * 4 + (threadIdx.x >> 6);
    const int lane = threadIdx.x & 63;
    const float* src; unsigned short* dst; float* sqp; int r;
    if (row < M_DIM) { src = X; dst = Xb; sqp = sq1; r = row; }
    else             { src = T; dst = Tb; sqp = sq2; r = row - M_DIM; }

    const float4* s4 = reinterpret_cast<const float4*>(src + (size_t)r * D_DIM);
    float4 v = s4[lane];
    float ss = v.x * v.x + v.y * v.y + v.z * v.z + v.w * v.w;

    ushort4 b4;
    b4.x = f2bf(v.x); b4.y = f2bf(v.y); b4.z = f2bf(v.z); b4.w = f2bf(v.w);
    reinterpret_cast<ushort4*>(dst + (size_t)r * D_DIM)[lane] = b4;

    #pragma unroll
    for (int o = 1; o < 64; o <<= 1) ss += __shfl_xor(ss, o);
    if (lane == 0) sqp[r] = ss;
}

// ---------------------------------------------------------------------------
// Fused RBF GEMM, m97 structure: 128x128 tile, BK=64 K-loop (4 steps),
// single-buffered 32 KiB LDS -> 3-4 blocks/CU for inter-block overlap.
// LDS rows are 128 B (exactly 32 banks); 16 B slot XOR-swizzled by row&7
// on BOTH the pre-swizzled global source and the ds_read address (G21).
// Epilogue: exp + alpha-weighted row reduce + one atomicAdd per (row,wave).
// ---------------------------------------------------------------------------
__global__ __launch_bounds__(256) void gemm_kernel(
    const unsigned short* __restrict__ Xb, const unsigned short* __restrict__ Tb,
    const float* __restrict__ sq1, const float* __restrict__ sq2,
    const float* __restrict__ alpha, float* __restrict__ out)
{
    __shared__ __align__(16) char smem[2 * STEP_BYTES]; // 32 KiB
    char* As = smem;
    char* Bs = smem + STEP_BYTES;

    const int bm   = blockIdx.x & 31;   // bm fastest: XCD x sees only bm%8==x
    const int bn   = blockIdx.x >> 5;   // -> per-XCD A set = 256 KB, L2-resident
    const int tid  = threadIdx.x;
    const int wid  = tid >> 6;          // wave 0..3
    const int lane = tid & 63;

    const char* gA = (const char*)(Xb + (size_t)bm * BM * D_DIM);
    const char* gB = (const char*)(Tb + (size_t)bn * BN * D_DIM);

    // Staging decomposition: 16 chunks of 1 KiB (8 rows x 128 B) per tile
    // per step; 4 A-chunks + 4 B-chunks per wave per step.
    // Lane l -> row-in-chunk rsub=l>>3, slot=l&7. LDS[r][s] = G[r][s^(r&7)],
    // and r&7 == rsub, so source slot = slot ^ rsub (per-lane constant).
    const int rsub = lane >> 3;
    const int sg16 = ((lane & 7) ^ rsub) * 16;

    const int wr  = wid >> 1, wc = wid & 1;  // 2x2 waves, 64x64 out each
    const int l15 = lane & 15;
    const int lg  = lane >> 4;
    const int xr  = l15 & 7;                 // row&7 for this lane's frag rows

    f32x4 acc[4][4];
    #pragma unroll
    for (int m = 0; m < 4; ++m)
        #pragma unroll
        for (int n = 0; n < 4; ++n) acc[m][n] = (f32x4)0.0f;

    int abase[4], bbase[4];
    #pragma unroll
    for (int m = 0; m < 4; ++m) abase[m] = (wr * 64 + m * 16 + l15) * 128;
    #pragma unroll
    for (int n = 0; n < 4; ++n) bbase[n] = (wc * 64 + n * 16 + l15) * 128;

    for (int kt = 0; kt < D_DIM / BK; ++kt) {
        const int ktb = kt * (BK * 2); // byte offset of this k-window in a row
        #pragma unroll
        for (int c = 0; c < 4; ++c) {
            const int chunk = wid * 4 + c;
            const int ob = chunk * 1024;                       // wave-uniform
            const size_t so = (size_t)(chunk * 8 + rsub) * (D_DIM * 2) + ktb + sg16;
            __builtin_amdgcn_global_load_lds(
                (const __attribute__((address_space(1))) void*)(gA + so),
                (__attribute__((address_space(3))) void*)(As + ob), 16, 0, 0);
            __builtin_amdgcn_global_load_lds(
                (const __attribute__((address_space(1))) void*)(gB + so),
                (__attribute__((address_space(3))) void*)(Bs + ob), 16, 0, 0);
        }
        __syncthreads(); // drains vmcnt: tiles ready

        #pragma unroll
        for (int kk = 0; kk < 2; ++kk) {
            const int ko = (((kk << 2) + lg) ^ xr) << 4; // swizzled slot byte
            short8 af[4], bf[4];
            #pragma unroll
            for (int m = 0; m < 4; ++m) af[m] = *(const short8*)(As + abase[m] + ko);
            #pragma unroll
            for (int n = 0; n < 4; ++n) bf[n] = *(const short8*)(Bs + bbase[n] + ko);
            #pragma unroll
            for (int m = 0; m < 4; ++m)
                #pragma unroll
                for (int n = 0; n < 4; ++n)
                    acc[m][n] = __builtin_amdgcn_mfma_f32_16x16x32_bf16(
                        af[m], bf[n], acc[m][n], 0, 0, 0);
        }
        __syncthreads(); // compute done before next stage overwrites
    }

    // Epilogue: C/D layout col=lane&15, row=(lane>>4)*4+reg (m89-verified).
    const int brow = bm * BM, bcol = bn * BN;
    float sq2c[4], alf[4];
    #pragma unroll
    for (int n = 0; n < 4; ++n) {
        const int gj = bcol + wc * 64 + n * 16 + l15;
        sq2c[n] = sq2[gj];
        alf[n]  = alpha[gj];
    }
    #pragma unroll
    for (int m = 0; m < 4; ++m) {
        #pragma unroll
        for (int r = 0; r < 4; ++r) {
            const int gi = brow + wr * 64 + m * 16 + lg * 4 + r;
            const float s1 = sq1[gi];
            float p = 0.0f;
            #pragma unroll
            for (int n = 0; n < 4; ++n) {
                const float d = s1 + sq2c[n] - 2.0f * acc[m][n][r];
                p += __expf(-0.5f * d) * alf[n];
            }
            // reduce over the 16 lanes (l15) holding this row's 64 columns
            p += __shfl_xor(p, 1);
            p += __shfl_xor(p, 2);
            p += __shfl_xor(p, 4);
            p += __shfl_xor(p, 8);
            if (l15 == 0) atomicAdd(&out[gi], p);
        }
    }
}

extern "C" void kernel_launch(void* const* d_in, const int* in_sizes, int n_in,
                              void* d_out, int out_size, void* d_ws, size_t ws_size,
                              hipStream_t stream)
{
    const float* X  = (const float*)d_in[0];
    const float* T  = (const float*)d_in[1];
    const float* al = (const float*)d_in[2];
    float* out = (float*)d_out;

    char* ws = (char*)d_ws;
    unsigned short* Xb = (unsigned short*)ws;                               // 2 MiB
    unsigned short* Tb = (unsigned short*)(ws + (size_t)M_DIM * D_DIM * 2); // 4 MiB
    float* sq1 = (float*)(ws + (size_t)(M_DIM + N_DIM) * D_DIM * 2);        // 16 KiB
    float* sq2 = sq1 + M_DIM;                                               // 32 KiB

    prep_kernel<<<(M_DIM + N_DIM) / 4, 256, 0, stream>>>(X, T, Xb, Tb, sq1, sq2, out);
    gemm_kernel<<<(M_DIM / BM) * (N_DIM / BN), 256, 0, stream>>>(Xb, Tb, sq1, sq2, al, out);
}